// Round 10
// baseline (1181.633 us; speedup 1.0000x reference)
//
#include <hip/hip_runtime.h>
#include <stdint.h>

#define N_CL 40000
#define NF   20
#define DD   128
#define SS   512
#define NW   625                 // N_CL / 64
#define PARTN (NW * SS)
#define NEGF (-3.0e38f)
#define DISCOUNT 0.995f
#define ECOEF 0.1f

typedef __attribute__((ext_vector_type(4))) float f32x4;
typedef __attribute__((ext_vector_type(16))) float f32x16;
typedef __attribute__((ext_vector_type(8))) short short8;
typedef __attribute__((ext_vector_type(4))) unsigned short us4;

__device__ __forceinline__ float rl(float v, int k) {
    return __int_as_float(__builtin_amdgcn_readlane(__float_as_int(v), k));
}
__device__ __forceinline__ float rcpf(float x) { return __builtin_amdgcn_rcpf(x); }
__device__ __forceinline__ float sigm(float x) { return rcpf(1.f + __expf(-x)); }
__device__ __forceinline__ float tanh_fast(float x) { return 1.f - 2.f * rcpf(1.f + __expf(2.f * x)); }
__device__ __forceinline__ unsigned short f2bf(float f) {
    unsigned u = __float_as_uint(f);
    return (unsigned short)((u + 0x7fffu + ((u >> 16) & 1u)) >> 16);   // RNE
}
__device__ __forceinline__ float bf2f(unsigned short s) {
    return __uint_as_float(((unsigned)s) << 16);
}

// ------- pack masks: ballot -> u64 words, TRANSPOSED layout [b][s] -------------
__global__ __launch_bounds__(256) void k_pack(const int* __restrict__ sel,
                                              const int* __restrict__ good,
                                              unsigned long long* __restrict__ selw,
                                              unsigned long long* __restrict__ goodw) {
    int wave = (blockIdx.x * 256 + threadIdx.x) >> 6;   // 0..4999
    int lane = threadIdx.x & 63;
    for (int i = 0; i < 64; ++i) {
        int chunk = wave * 64 + i;                      // 0..319999
        int s = chunk / NW;
        int b = chunk - s * NW;
        int idx = s * N_CL + b * 64 + lane;
        unsigned long long bs = __ballot(sel[idx]  != 0);
        unsigned long long bg = __ballot(good[idx] != 0);
        if (lane == 0) { selw[b * SS + s] = bs; goodw[b * SS + s] = bg; }
    }
}

// ---------------- hidden = relu(features @ W1 + b1) ----------------------------
__global__ __launch_bounds__(256) void k_hidden(const float* __restrict__ feat,
                                                const float* __restrict__ W1,
                                                const float* __restrict__ b1,
                                                float* __restrict__ hidden) {
    int t = threadIdx.x;
    int j = t & 127;
    int r = blockIdx.x * 2 + (t >> 7);
    const float* fr = feat + r * NF;
    float acc = b1[j];
#pragma unroll
    for (int f = 0; f < NF; ++f) acc += fr[f] * W1[f * DD + j];
    hidden[r * DD + j] = fmaxf(acc, 0.f);
}

// ------- emb = hidden @ W2 + b2, emitted as bf16 hi/lo pairs -------------------
#define EMB_FMA(RR) { f32x4 hvv = *(const f32x4*)&hs[rg * 8 + RR][q]; \
    acc##RR += wv0 * hvv.x + wv1 * hvv.y + wv2 * hvv.z + wv3 * hvv.w; }
#define EMB_ST(RR) { f32x4 f = acc##RR + bv; us4 hi, lo; \
    hi[0] = f2bf(f.x); lo[0] = f2bf(f.x - bf2f(hi[0])); \
    hi[1] = f2bf(f.y); lo[1] = f2bf(f.y - bf2f(hi[1])); \
    hi[2] = f2bf(f.z); lo[2] = f2bf(f.z - bf2f(hi[2])); \
    hi[3] = f2bf(f.w); lo[3] = f2bf(f.w - bf2f(hi[3])); \
    int row_ = rbase + rg * 8 + RR; \
    *(us4*)&emb_hi[row_ * DD + c4 * 4] = hi; \
    *(us4*)&emb_lo[row_ * DD + c4 * 4] = lo; }

__global__ __launch_bounds__(256) void k_emb(const float* __restrict__ hidden,
                                             const float* __restrict__ W2,
                                             const float* __restrict__ b2,
                                             unsigned short* __restrict__ emb_hi,
                                             unsigned short* __restrict__ emb_lo) {
    __shared__ float hs[64][132];                     // +4 pad, 33.8 KB
    int t = threadIdx.x;
    int rbase = blockIdx.x * 64;
#pragma unroll
    for (int i = t; i < 2048; i += 256) {             // stage 64x128 hidden tile
        int r = i >> 5, k4 = i & 31;
        *(f32x4*)&hs[r][k4 * 4] = *(const f32x4*)&hidden[(rbase + r) * DD + k4 * 4];
    }
    __syncthreads();
    int c4 = t & 31, rg = t >> 5;
    f32x4 acc0{0,0,0,0}, acc1{0,0,0,0}, acc2{0,0,0,0}, acc3{0,0,0,0},
          acc4{0,0,0,0}, acc5{0,0,0,0}, acc6{0,0,0,0}, acc7{0,0,0,0};
    for (int q = 0; q < DD; q += 4) {
        f32x4 wv0 = *(const f32x4*)&W2[(q + 0) * DD + c4 * 4];
        f32x4 wv1 = *(const f32x4*)&W2[(q + 1) * DD + c4 * 4];
        f32x4 wv2 = *(const f32x4*)&W2[(q + 2) * DD + c4 * 4];
        f32x4 wv3 = *(const f32x4*)&W2[(q + 3) * DD + c4 * 4];
        EMB_FMA(0) EMB_FMA(1) EMB_FMA(2) EMB_FMA(3)
        EMB_FMA(4) EMB_FMA(5) EMB_FMA(6) EMB_FMA(7)
    }
    f32x4 bv = *(const f32x4*)&b2[c4 * 4];
    EMB_ST(0) EMB_ST(1) EMB_ST(2) EMB_ST(3)
    EMB_ST(4) EMB_ST(5) EMB_ST(6) EMB_ST(7)
}

// ---- P3[s][pos][e][slot] = bih[j]+bhh[j]+Wih[j].emb[sel_idx[s]] ---------------
// gate j = g*128+pos maps to e=g&1, slot=g>>1: (i,g) in e=0, (f,o) in e=1.
__global__ __launch_bounds__(256) void k_pgemm(const unsigned short* __restrict__ emb_hi,
                                               const unsigned short* __restrict__ emb_lo,
                                               const int* __restrict__ sel_idx,
                                               const float* __restrict__ Wih,
                                               const float* __restrict__ bih,
                                               const float* __restrict__ bhh,
                                               float* __restrict__ P3) {
    __shared__ __align__(16) float x8[8][DD];
    int t = threadIdx.x;
    int sb = blockIdx.x * 8;
    for (int i = t; i < 8 * DD; i += 256) {
        int sl = i >> 7, k = i & 127;
        int idx = sel_idx[sb + sl] * DD + k;
        x8[sl][k] = bf2f(emb_hi[idx]) + bf2f(emb_lo[idx]);
    }
    __syncthreads();
    for (int jj = t; jj < 512; jj += 256) {
        float base = bih[jj] + bhh[jj];
        float acc[8];
#pragma unroll
        for (int s8 = 0; s8 < 8; ++s8) acc[s8] = base;
        const float4* wr = (const float4*)(Wih + jj * DD);
        for (int q = 0; q < 32; ++q) {
            float4 w4 = wr[q];
#pragma unroll
            for (int s8 = 0; s8 < 8; ++s8) {
                const float4* xs = (const float4*)&x8[s8][0];
                float4 xv = xs[q];
                acc[s8] += w4.x * xv.x + w4.y * xv.y + w4.z * xv.z + w4.w * xv.w;
            }
        }
        int pos = jj & 127, g = jj >> 7;
        int oidx = pos * 4 + (g & 1) * 2 + (g >> 1);
        for (int s8 = 0; s8 < 8; ++s8) P3[(sb + s8) * 512 + oidx] = acc[s8];
    }
}

// ------- sequential LSTM scan: 256 thr = 4 waves = 1 wave/SIMD -----------------
// Thread t: position p=t>>1, parity e=t&1. Owns full-K rows e*128+p (i or f)
// and (2+e)*128+p (g or o). Shared readlane feeds both rows (128 rl + 256 fma).
// No psum LDS; gate exchange = 2 shfl_xor(1) in the lane pair; ONE barrier/step.
#define MVP(WA, WB, HV, L) { \
    float s0 = rl(HV, (L) + 0), s1 = rl(HV, (L) + 1), \
          s2 = rl(HV, (L) + 2), s3 = rl(HV, (L) + 3); \
    aA0 = fmaf(WA.x, s0, aA0); aB0 = fmaf(WB.x, s0, aB0); \
    aA1 = fmaf(WA.y, s1, aA1); aB1 = fmaf(WB.y, s1, aB1); \
    aA2 = fmaf(WA.z, s2, aA2); aB2 = fmaf(WB.z, s2, aB2); \
    aA3 = fmaf(WA.w, s3, aA3); aB3 = fmaf(WB.w, s3, aB3); }

__global__ __launch_bounds__(256, 1) void k_lstm(const float* __restrict__ Whh,
                                                 const float* __restrict__ P3,
                                                 const float* __restrict__ init_h,
                                                 const float* __restrict__ init_c,
                                                 unsigned short* __restrict__ Hhi,
                                                 unsigned short* __restrict__ Hlo) {
    __shared__ float h_sh[2][DD];                   // double-buffered hidden
    int t = threadIdx.x, l = t & 63;
    int e = t & 1, p = t >> 1;

    const f32x4* wra = (const f32x4*)(Whh + (e * DD + p) * DD);        // i or f
    const f32x4* wrb = (const f32x4*)(Whh + ((2 + e) * DD + p) * DD);  // g or o
    f32x4 wa0 = wra[0],  wa1 = wra[1],  wa2 = wra[2],  wa3 = wra[3],
          wa4 = wra[4],  wa5 = wra[5],  wa6 = wra[6],  wa7 = wra[7],
          wa8 = wra[8],  wa9 = wra[9],  wa10 = wra[10], wa11 = wra[11],
          wa12 = wra[12], wa13 = wra[13], wa14 = wra[14], wa15 = wra[15],
          wa16 = wra[16], wa17 = wra[17], wa18 = wra[18], wa19 = wra[19],
          wa20 = wra[20], wa21 = wra[21], wa22 = wra[22], wa23 = wra[23],
          wa24 = wra[24], wa25 = wra[25], wa26 = wra[26], wa27 = wra[27],
          wa28 = wra[28], wa29 = wra[29], wa30 = wra[30], wa31 = wra[31];
    f32x4 wb0 = wrb[0],  wb1 = wrb[1],  wb2 = wrb[2],  wb3 = wrb[3],
          wb4 = wrb[4],  wb5 = wrb[5],  wb6 = wrb[6],  wb7 = wrb[7],
          wb8 = wrb[8],  wb9 = wrb[9],  wb10 = wrb[10], wb11 = wrb[11],
          wb12 = wrb[12], wb13 = wrb[13], wb14 = wrb[14], wb15 = wrb[15],
          wb16 = wrb[16], wb17 = wrb[17], wb18 = wrb[18], wb19 = wrb[19],
          wb20 = wrb[20], wb21 = wrb[21], wb22 = wrb[22], wb23 = wrb[23],
          wb24 = wrb[24], wb25 = wrb[25], wb26 = wrb[26], wb27 = wrb[27],
          wb28 = wrb[28], wb29 = wrb[29], wb30 = wrb[30], wb31 = wrb[31];

    float c = init_c[p];                            // replicated per lane pair
    if (t < DD) {
        float f = init_h[t];
        h_sh[0][t] = f;
        unsigned short hi = f2bf(f);
        Hhi[t] = hi; Hlo[t] = f2bf(f - bf2f(hi));
    }
    __syncthreads();

    // v2 nonlinearity: e=0 -> tanh (g-gate), e=1 -> sigmoid (o-gate)
    float na = e ? -1.f : 2.f;
    float nk = e ? 1.f : -2.f;
    float nb = e ? 0.f : 1.f;
    float hbuf[8];
    for (int s = 0; s < SS; ++s) {
        int cur = s & 1, nxt = cur ^ 1;
        float2 pv = *(const float2*)&P3[s * 512 + p * 4 + e * 2];   // L2, hidden under matvec
        float vh0 = h_sh[cur][l], vh1 = h_sh[cur][64 + l];
        float aA0 = 0.f, aA1 = 0.f, aA2 = 0.f, aA3 = 0.f;
        float aB0 = 0.f, aB1 = 0.f, aB2 = 0.f, aB3 = 0.f;
        MVP(wa0,  wb0,  vh0, 0)  MVP(wa1,  wb1,  vh0, 4)
        MVP(wa2,  wb2,  vh0, 8)  MVP(wa3,  wb3,  vh0, 12)
        MVP(wa4,  wb4,  vh0, 16) MVP(wa5,  wb5,  vh0, 20)
        MVP(wa6,  wb6,  vh0, 24) MVP(wa7,  wb7,  vh0, 28)
        MVP(wa8,  wb8,  vh0, 32) MVP(wa9,  wb9,  vh0, 36)
        MVP(wa10, wb10, vh0, 40) MVP(wa11, wb11, vh0, 44)
        MVP(wa12, wb12, vh0, 48) MVP(wa13, wb13, vh0, 52)
        MVP(wa14, wb14, vh0, 56) MVP(wa15, wb15, vh0, 60)
        MVP(wa16, wb16, vh1, 0)  MVP(wa17, wb17, vh1, 4)
        MVP(wa18, wb18, vh1, 8)  MVP(wa19, wb19, vh1, 12)
        MVP(wa20, wb20, vh1, 16) MVP(wa21, wb21, vh1, 20)
        MVP(wa22, wb22, vh1, 24) MVP(wa23, wb23, vh1, 28)
        MVP(wa24, wb24, vh1, 32) MVP(wa25, wb25, vh1, 36)
        MVP(wa26, wb26, vh1, 40) MVP(wa27, wb27, vh1, 44)
        MVP(wa28, wb28, vh1, 48) MVP(wa29, wb29, vh1, 52)
        MVP(wa30, wb30, vh1, 56) MVP(wa31, wb31, vh1, 60)
        float aA = ((aA0 + aA1) + (aA2 + aA3)) + pv.x;   // i (e=0) or f (e=1)
        float aB = ((aB0 + aB1) + (aB2 + aB3)) + pv.y;   // g (e=0) or o (e=1)
        float v1 = sigm(aA);                             // i or f
        float v2 = fmaf(rcpf(1.f + __expf(na * aB)), nk, nb);  // tanh(g) or sigm(o)
        float o1 = __shfl_xor(v1, 1);                    // partner's i/f
        float o2 = __shfl_xor(v2, 1);                    // partner's g/o
        float ii = e ? o1 : v1;
        float ff = e ? v1 : o1;
        float tg = e ? o2 : v2;
        float oo = e ? v2 : o2;
        c = ff * c + ii * tg;
        float hn = oo * tanh_fast(c);
        if (e == 0) h_sh[nxt][p] = hn;
        if (s < SS - 1) {
            hbuf[s & 7] = hn;
            if ((s & 7) == 7 && e == 0) {                // batched H store, 1/8 steps
#pragma unroll
                for (int k2 = 0; k2 < 8; ++k2) {
                    float f = hbuf[k2];
                    unsigned short hi = f2bf(f);
                    Hhi[(s - 6 + k2) * DD + p] = hi;
                    Hlo[(s - 6 + k2) * DD + p] = f2bf(f - bf2f(hi));
                }
            }
        }
        __syncthreads();                                 // the ONE barrier per step
    }
    if (e == 0) {                                        // steps 504..510 -> H[505..511]
#pragma unroll
        for (int k2 = 0; k2 < 7; ++k2) {
            float f = hbuf[k2];
            unsigned short hi = f2bf(f);
            Hhi[(505 + k2) * DD + p] = hi;
            Hlo[(505 + k2) * DD + p] = f2bf(f - bf2f(hi));
        }
    }
}

// ------- phase C: MFMA GEMM logits + masked-softmax epilogue -------------------
// Grid 2500: b = blk>>2 (64-row tile), (blk&3, wave) -> 32-step group.
__global__ __launch_bounds__(256, 1) void k_logits(
        const unsigned short* __restrict__ emb_hi,
        const unsigned short* __restrict__ emb_lo,
        const unsigned short* __restrict__ Hhi,
        const unsigned short* __restrict__ Hlo,
        const unsigned long long* __restrict__ selw,
        const unsigned long long* __restrict__ goodw,
        float* __restrict__ part) {
    int blk = blockIdx.x;
    int b = blk >> 2;
    int t = threadIdx.x, wv = t >> 6, l = t & 63;
    int s0 = (blk & 3) * 128 + wv * 32;
    int ln = l & 31, lh = l >> 5;
    int rb = b * 64;
    const short8* A0h = (const short8*)(emb_hi + (rb + ln) * DD + lh * 8);
    const short8* A0l = (const short8*)(emb_lo + (rb + ln) * DD + lh * 8);
    const short8* A1h = (const short8*)(emb_hi + (rb + 32 + ln) * DD + lh * 8);
    const short8* A1l = (const short8*)(emb_lo + (rb + 32 + ln) * DD + lh * 8);
    const short8* Bhp = (const short8*)(Hhi + (s0 + ln) * DD + lh * 8);
    const short8* Blp = (const short8*)(Hlo + (s0 + ln) * DD + lh * 8);
    f32x16 acc0, acc1;
#pragma unroll
    for (int r = 0; r < 16; ++r) { acc0[r] = 0.f; acc1[r] = 0.f; }
#pragma unroll
    for (int kc = 0; kc < 8; ++kc) {               // K = 8 x 16
        short8 a0h = A0h[kc * 2], a0l = A0l[kc * 2];
        short8 a1h = A1h[kc * 2], a1l = A1l[kc * 2];
        short8 bh = Bhp[kc * 2], bl = Blp[kc * 2];
        acc0 = __builtin_amdgcn_mfma_f32_32x32x16_bf16(a0h, bh, acc0, 0, 0, 0);
        acc0 = __builtin_amdgcn_mfma_f32_32x32x16_bf16(a0l, bh, acc0, 0, 0, 0);
        acc0 = __builtin_amdgcn_mfma_f32_32x32x16_bf16(a0h, bl, acc0, 0, 0, 0);
        acc1 = __builtin_amdgcn_mfma_f32_32x32x16_bf16(a1h, bh, acc1, 0, 0, 0);
        acc1 = __builtin_amdgcn_mfma_f32_32x32x16_bf16(a1l, bh, acc1, 0, 0, 0);
        acc1 = __builtin_amdgcn_mfma_f32_32x32x16_bf16(a1h, bl, acc1, 0, 0, 0);
    }
    int s = s0 + ln;
    unsigned long long sw = selw[b * SS + s];      // coalesced, [b][s] layout
    unsigned long long gw = goodw[b * SS + s];
    float m = NEGF;
#pragma unroll
    for (int r = 0; r < 16; ++r) {
        int row = (r & 3) + 8 * (r >> 2) + 4 * lh;
        float v0 = acc0[r], v1 = acc1[r];
        m = fmaxf(m, ((sw >> row) & 1ull) ? v0 : NEGF);
        m = fmaxf(m, ((sw >> (row + 32)) & 1ull) ? v1 : NEGF);
    }
    m = fmaxf(m, __shfl_xor(m, 32));
    float se = 0.f, sl = 0.f, slg = 0.f;
#pragma unroll
    for (int r = 0; r < 16; ++r) {
        int row = (r & 3) + 8 * (r >> 2) + 4 * lh;
        float v0 = acc0[r], v1 = acc1[r];
        float e0 = ((sw >> row) & 1ull) ? __expf(v0 - m) : 0.f;
        float e1 = ((sw >> (row + 32)) & 1ull) ? __expf(v1 - m) : 0.f;
        se += e0 + e1;
        sl += e0 * v0 + e1 * v1;
        slg += (((gw >> row) & 1ull) ? v0 : 0.f)
             + (((gw >> (row + 32)) & 1ull) ? v1 : 0.f);
    }
    se += __shfl_xor(se, 32);
    sl += __shfl_xor(sl, 32);
    slg += __shfl_xor(slg, 32);
    if (lh == 0) {
        int o = s * NW + b;                        // TRANSPOSED part: [s][b]
        part[0 * PARTN + o] = m;
        part[1 * PARTN + o] = se;
        part[2 * PARTN + o] = sl;
        part[3 * PARTN + o] = slg;
        part[4 * PARTN + o] = (float)__popcll(sw);
        part[5 * PARTN + o] = (float)__popcll(gw);
    }
}

// ------- per-step merge of 625 block partials (coalesced [s][b] reads) ---------
__global__ __launch_bounds__(64) void k_reduce(const float* __restrict__ part,
                                               float* __restrict__ Aout,
                                               float* __restrict__ Bout,
                                               float* __restrict__ actout) {
    int s = blockIdx.x;
    int t = threadIdx.x;     // 64 threads, one wave
    float m = NEGF, se = 0.f, sl = 0.f, slg = 0.f, np = 0.f, ng = 0.f;
    for (int b = t; b < NW; b += 64) {
        int o = s * NW + b;                        // lanes consecutive
        float m2  = part[0 * PARTN + o];
        float se2 = part[1 * PARTN + o];
        float sl2 = part[2 * PARTN + o];
        slg += part[3 * PARTN + o];
        np  += part[4 * PARTN + o];
        ng  += part[5 * PARTN + o];
        float nm = fmaxf(m, m2);
        float a = __expf(m - nm), a2 = __expf(m2 - nm);
        se = se * a + se2 * a2;
        sl = sl * a + sl2 * a2;
        m = nm;
    }
    for (int off = 32; off > 0; off >>= 1) {
        float m2  = __shfl_xor(m, off);
        float se2 = __shfl_xor(se, off);
        float sl2 = __shfl_xor(sl, off);
        slg += __shfl_xor(slg, off);
        np  += __shfl_xor(np, off);
        ng  += __shfl_xor(ng, off);
        float nm = fmaxf(m, m2);
        float a = __expf(m - nm), a2 = __expf(m2 - nm);
        se = se * a + se2 * a2;
        sl = sl * a + sl2 * a2;
        m = nm;
    }
    if (t == 0) {
        float lse = m + logf(se);
        float nbad = np - ng;
        int active = (ng > 0.5f) && (nbad > 0.5f);
        float ce = (ng * lse - slg) / fmaxf(ng, 1.f);
        float A = (nbad / fmaxf(np, 1.f)) * ce;
        float minus_ent = sl / se - lse;
        float B = ECOEF * (minus_ent / logf(fmaxf(np, 2.0f)));
        Aout[s] = A; Bout[s] = B; actout[s] = active ? 1.f : 0.f;
    }
}

// ---------------- exact sequential discount prefix + final sum -----------------
__global__ __launch_bounds__(64) void k_final(const float* __restrict__ A,
                                              const float* __restrict__ B,
                                              const float* __restrict__ act,
                                              float* __restrict__ out) {
    int lane = threadIdx.x;
    float loss = 0.f;
    int base = 0;
    for (int ch = 0; ch < 8; ++ch) {
        int s = ch * 64 + lane;
        bool a = act[s] > 0.5f;
        unsigned long long bal = __ballot(a);
        unsigned long long ltmask = (lane == 0) ? 0ull : (~0ull >> (64 - lane));
        int pre = __popcll(bal & ltmask);
        if (a) {
            float f = powf(DISCOUNT, (float)(base + pre));
            loss += f * A[s] + B[s];
        }
        base += __popcll(bal);
    }
    for (int off = 32; off > 0; off >>= 1) loss += __shfl_xor(loss, off);
    if (lane == 0) out[0] = loss / fmaxf((float)base, 1.f);
}

extern "C" void kernel_launch(void* const* d_in, const int* in_sizes, int n_in,
                              void* d_out, int out_size, void* d_ws, size_t ws_size,
                              hipStream_t stream) {
    (void)in_sizes; (void)n_in; (void)out_size; (void)ws_size;
    const float* feat    = (const float*)d_in[0];
    const int*   sel     = (const int*)d_in[1];
    const int*   good    = (const int*)d_in[2];
    const int*   sel_idx = (const int*)d_in[3];
    const float* W1      = (const float*)d_in[4];
    const float* b1      = (const float*)d_in[5];
    const float* W2      = (const float*)d_in[6];
    const float* b2      = (const float*)d_in[7];
    const float* init_h  = (const float*)d_in[8];
    const float* init_c  = (const float*)d_in[9];
    const float* Wih     = (const float*)d_in[10];
    const float* Whh     = (const float*)d_in[11];
    const float* bih     = (const float*)d_in[12];
    const float* bhh     = (const float*)d_in[13];
    float* out = (float*)d_out;
    char* ws = (char*)d_ws;

    float*          hidden = (float*)(ws + 0);                    // 20,480,000 B
    unsigned short* emb_hi = (unsigned short*)(ws + 20480000);    // 10,240,000 B
    unsigned short* emb_lo = (unsigned short*)(ws + 30720000);    // 10,240,000 B
    float*          P3     = (float*)(ws + 40960000);             //  1,048,576 B
    unsigned short* Hhi    = (unsigned short*)(ws + 42008576);    //    131,072 B
    unsigned short* Hlo    = (unsigned short*)(ws + 42139648);    //    131,072 B
    unsigned long long* selw  = (unsigned long long*)(ws + 42270720);  // 2,560,000 B
    unsigned long long* goodw = (unsigned long long*)(ws + 44830720);  // 2,560,000 B
    float*          part   = (float*)(ws + 47390720);             //  7,680,000 B
    float*          Aarr   = (float*)(ws + 55070720);             //      2,048 B
    float*          Barr   = (float*)(ws + 55072768);             //      2,048 B
    float*          actarr = (float*)(ws + 55074816);             //      2,048 B

    k_pack  <<<1250, 256, 0, stream>>>(sel, good, selw, goodw);
    k_hidden<<<N_CL / 2, 256, 0, stream>>>(feat, W1, b1, hidden);
    k_emb   <<<NW, 256, 0, stream>>>(hidden, W2, b2, emb_hi, emb_lo);
    k_pgemm <<<64, 256, 0, stream>>>(emb_hi, emb_lo, sel_idx, Wih, bih, bhh, P3);
    k_lstm  <<<1, 256, 0, stream>>>(Whh, P3, init_h, init_c, Hhi, Hlo);
    k_logits<<<NW * 4, 256, 0, stream>>>(emb_hi, emb_lo, Hhi, Hlo, selw, goodw, part);
    k_reduce<<<SS, 64, 0, stream>>>(part, Aarr, Barr, actarr);
    k_final <<<1, 64, 0, stream>>>(Aarr, Barr, actarr, out);
}

// Round 11
// 915.244 us; speedup vs baseline: 1.2911x; 1.2911x over previous
//
#include <hip/hip_runtime.h>
#include <stdint.h>

#define N_CL 40000
#define NF   20
#define DD   128
#define SS   512
#define NW   625                 // N_CL / 64
#define PARTN (NW * SS)
#define NEGF (-3.0e38f)
#define DISCOUNT 0.995f
#define ECOEF 0.1f

typedef __attribute__((ext_vector_type(4))) float f32x4;
typedef __attribute__((ext_vector_type(16))) float f32x16;
typedef __attribute__((ext_vector_type(8))) short short8;
typedef __attribute__((ext_vector_type(4))) unsigned short us4;

__device__ __forceinline__ float rcpf(float x) { return __builtin_amdgcn_rcpf(x); }
__device__ __forceinline__ float sigm(float x) { return rcpf(1.f + __expf(-x)); }
__device__ __forceinline__ float tanh_fast(float x) { return 1.f - 2.f * rcpf(1.f + __expf(2.f * x)); }
__device__ __forceinline__ unsigned short f2bf(float f) {
    unsigned u = __float_as_uint(f);
    return (unsigned short)((u + 0x7fffu + ((u >> 16) & 1u)) >> 16);   // RNE
}
__device__ __forceinline__ float bf2f(unsigned short s) {
    return __uint_as_float(((unsigned)s) << 16);
}

// ------- pack masks: ballot -> u64 words, TRANSPOSED layout [b][s] -------------
__global__ __launch_bounds__(256) void k_pack(const int* __restrict__ sel,
                                              const int* __restrict__ good,
                                              unsigned long long* __restrict__ selw,
                                              unsigned long long* __restrict__ goodw) {
    int wave = (blockIdx.x * 256 + threadIdx.x) >> 6;   // 0..4999
    int lane = threadIdx.x & 63;
    for (int i = 0; i < 64; ++i) {
        int chunk = wave * 64 + i;                      // 0..319999
        int s = chunk / NW;
        int b = chunk - s * NW;
        int idx = s * N_CL + b * 64 + lane;
        unsigned long long bs = __ballot(sel[idx]  != 0);
        unsigned long long bg = __ballot(good[idx] != 0);
        if (lane == 0) { selw[b * SS + s] = bs; goodw[b * SS + s] = bg; }
    }
}

// ---------------- hidden = relu(features @ W1 + b1) ----------------------------
__global__ __launch_bounds__(256) void k_hidden(const float* __restrict__ feat,
                                                const float* __restrict__ W1,
                                                const float* __restrict__ b1,
                                                float* __restrict__ hidden) {
    int t = threadIdx.x;
    int j = t & 127;
    int r = blockIdx.x * 2 + (t >> 7);
    const float* fr = feat + r * NF;
    float acc = b1[j];
#pragma unroll
    for (int f = 0; f < NF; ++f) acc += fr[f] * W1[f * DD + j];
    hidden[r * DD + j] = fmaxf(acc, 0.f);
}

// ------- emb = hidden @ W2 + b2, emitted as bf16 hi/lo pairs -------------------
#define EMB_FMA(RR) { f32x4 hvv = *(const f32x4*)&hs[rg * 8 + RR][q]; \
    acc##RR += wv0 * hvv.x + wv1 * hvv.y + wv2 * hvv.z + wv3 * hvv.w; }
#define EMB_ST(RR) { f32x4 f = acc##RR + bv; us4 hi, lo; \
    hi[0] = f2bf(f.x); lo[0] = f2bf(f.x - bf2f(hi[0])); \
    hi[1] = f2bf(f.y); lo[1] = f2bf(f.y - bf2f(hi[1])); \
    hi[2] = f2bf(f.z); lo[2] = f2bf(f.z - bf2f(hi[2])); \
    hi[3] = f2bf(f.w); lo[3] = f2bf(f.w - bf2f(hi[3])); \
    int row_ = rbase + rg * 8 + RR; \
    *(us4*)&emb_hi[row_ * DD + c4 * 4] = hi; \
    *(us4*)&emb_lo[row_ * DD + c4 * 4] = lo; }

__global__ __launch_bounds__(256) void k_emb(const float* __restrict__ hidden,
                                             const float* __restrict__ W2,
                                             const float* __restrict__ b2,
                                             unsigned short* __restrict__ emb_hi,
                                             unsigned short* __restrict__ emb_lo) {
    __shared__ float hs[64][132];                     // +4 pad, 33.8 KB
    int t = threadIdx.x;
    int rbase = blockIdx.x * 64;
#pragma unroll
    for (int i = t; i < 2048; i += 256) {             // stage 64x128 hidden tile
        int r = i >> 5, k4 = i & 31;
        *(f32x4*)&hs[r][k4 * 4] = *(const f32x4*)&hidden[(rbase + r) * DD + k4 * 4];
    }
    __syncthreads();
    int c4 = t & 31, rg = t >> 5;
    f32x4 acc0{0,0,0,0}, acc1{0,0,0,0}, acc2{0,0,0,0}, acc3{0,0,0,0},
          acc4{0,0,0,0}, acc5{0,0,0,0}, acc6{0,0,0,0}, acc7{0,0,0,0};
    for (int q = 0; q < DD; q += 4) {
        f32x4 wv0 = *(const f32x4*)&W2[(q + 0) * DD + c4 * 4];
        f32x4 wv1 = *(const f32x4*)&W2[(q + 1) * DD + c4 * 4];
        f32x4 wv2 = *(const f32x4*)&W2[(q + 2) * DD + c4 * 4];
        f32x4 wv3 = *(const f32x4*)&W2[(q + 3) * DD + c4 * 4];
        EMB_FMA(0) EMB_FMA(1) EMB_FMA(2) EMB_FMA(3)
        EMB_FMA(4) EMB_FMA(5) EMB_FMA(6) EMB_FMA(7)
    }
    f32x4 bv = *(const f32x4*)&b2[c4 * 4];
    EMB_ST(0) EMB_ST(1) EMB_ST(2) EMB_ST(3)
    EMB_ST(4) EMB_ST(5) EMB_ST(6) EMB_ST(7)
}

// ---- P2[s][pos][g] = bih[j]+bhh[j]+Wih[j].emb[sel_idx[s]],  j=g*128+pos ------
__global__ __launch_bounds__(256) void k_pgemm(const unsigned short* __restrict__ emb_hi,
                                               const unsigned short* __restrict__ emb_lo,
                                               const int* __restrict__ sel_idx,
                                               const float* __restrict__ Wih,
                                               const float* __restrict__ bih,
                                               const float* __restrict__ bhh,
                                               float* __restrict__ P2) {
    __shared__ __align__(16) float x8[8][DD];
    int t = threadIdx.x;
    int sb = blockIdx.x * 8;
    for (int i = t; i < 8 * DD; i += 256) {
        int sl = i >> 7, k = i & 127;
        int idx = sel_idx[sb + sl] * DD + k;
        x8[sl][k] = bf2f(emb_hi[idx]) + bf2f(emb_lo[idx]);
    }
    __syncthreads();
    for (int jj = t; jj < 512; jj += 256) {
        float base = bih[jj] + bhh[jj];
        float acc[8];
#pragma unroll
        for (int s8 = 0; s8 < 8; ++s8) acc[s8] = base;
        const float4* wr = (const float4*)(Wih + jj * DD);
        for (int q = 0; q < 32; ++q) {
            float4 w4 = wr[q];
#pragma unroll
            for (int s8 = 0; s8 < 8; ++s8) {
                const float4* xs = (const float4*)&x8[s8][0];
                float4 xv = xs[q];
                acc[s8] += w4.x * xv.x + w4.y * xv.y + w4.z * xv.z + w4.w * xv.w;
            }
        }
        int pos = jj & 127, g = jj >> 7;
        for (int s8 = 0; s8 < 8; ++s8) P2[(sb + s8) * 512 + pos * 4 + g] = acc[s8];
    }
}

// ------- sequential LSTM scan: r5 skeleton, pk-fma matvec, NO readlanes --------
// 512 threads = 8 waves, 2 waves/SIMD. Thread t owns gate t (row Whh[t]).
// h broadcast via wave-uniform ds_read_b128 (32/thread) + f32x4 ops -> pk_fma:
// ~96 instr/wave matvec vs r5's ~384 (readlane + fma + accvgpr reads).
#define LF(Q, A) A += w##Q * hp[Q];

__global__ __launch_bounds__(512, 1) void k_lstm(const float* __restrict__ Whh,
                                                 const float* __restrict__ P2,
                                                 const float* __restrict__ init_h,
                                                 const float* __restrict__ init_c,
                                                 unsigned short* __restrict__ Hhi,
                                                 unsigned short* __restrict__ Hlo) {
    __shared__ __align__(16) float pbuf[2][4096];   // 32 KB: two 8-step P chunks
    __shared__ __align__(16) float gates_sh[512];   // [pos*4 + gtype]
    __shared__ __align__(16) float h_sh[2][DD];     // double-buffered hidden
    int t = threadIdx.x, w = t >> 6, l = t & 63;
    int pos = t & 127;

    const f32x4* wr = (const f32x4*)(Whh + t * DD);
    f32x4 w0 = wr[0],  w1 = wr[1],  w2 = wr[2],  w3 = wr[3],
          w4 = wr[4],  w5 = wr[5],  w6 = wr[6],  w7 = wr[7],
          w8 = wr[8],  w9 = wr[9],  w10 = wr[10], w11 = wr[11],
          w12 = wr[12], w13 = wr[13], w14 = wr[14], w15 = wr[15],
          w16 = wr[16], w17 = wr[17], w18 = wr[18], w19 = wr[19],
          w20 = wr[20], w21 = wr[21], w22 = wr[22], w23 = wr[23],
          w24 = wr[24], w25 = wr[25], w26 = wr[26], w27 = wr[27],
          w28 = wr[28], w29 = wr[29], w30 = wr[30], w31 = wr[31];

    auto issue = [&](int cidx, int bufi) {          // stage one 8-step P chunk
        if (cidx >= SS / 8) return;
        const float* src = P2 + cidx * 4096 + w * 512 + l * 4;
        float* dst = &pbuf[bufi][w * 512];
#pragma unroll
        for (int i = 0; i < 2; ++i) {
            __builtin_amdgcn_global_load_lds(
                (const __attribute__((address_space(1))) void*)(src + i * 256),
                (__attribute__((address_space(3))) void*)(dst + i * 256),
                16, 0, 0);
        }
    };

    float c = 0.f;
    if (t < DD) {
        float f = init_h[t];
        h_sh[0][t] = f; c = init_c[t];
        unsigned short hi = f2bf(f);
        Hhi[t] = hi; Hlo[t] = f2bf(f - bf2f(hi));
    }
    issue(0, 0);
    __syncthreads();

    float hbuf[8];
    for (int s = 0; s < SS; ++s) {
        int cur = s & 1, nxt = cur ^ 1;
        int buf = (s >> 3) & 1;
        if ((s & 7) == 0) issue((s >> 3) + 1, buf ^ 1);
        const f32x4* hp = (const f32x4*)&h_sh[cur][0];  // wave-uniform ds_read_b128
        f32x4 acc0{0,0,0,0}, acc1{0,0,0,0}, acc2{0,0,0,0}, acc3{0,0,0,0};
        LF(0,  acc0) LF(1,  acc1) LF(2,  acc2) LF(3,  acc3)
        LF(4,  acc0) LF(5,  acc1) LF(6,  acc2) LF(7,  acc3)
        LF(8,  acc0) LF(9,  acc1) LF(10, acc2) LF(11, acc3)
        LF(12, acc0) LF(13, acc1) LF(14, acc2) LF(15, acc3)
        LF(16, acc0) LF(17, acc1) LF(18, acc2) LF(19, acc3)
        LF(20, acc0) LF(21, acc1) LF(22, acc2) LF(23, acc3)
        LF(24, acc0) LF(25, acc1) LF(26, acc2) LF(27, acc3)
        LF(28, acc0) LF(29, acc1) LF(30, acc2) LF(31, acc3)
        f32x4 ss = (acc0 + acc1) + (acc2 + acc3);
        gates_sh[pos * 4 + (t >> 7)] = (ss.x + ss.y) + (ss.z + ss.w);
        __syncthreads();
        if (t < DD) {
            float4 pv = *(const float4*)&pbuf[buf][(s & 7) * 512 + t * 4];
            float4 gv = *(const float4*)&gates_sh[t * 4];
            float gi = gv.x + pv.x;
            float gf = gv.y + pv.y;
            float gg = gv.z + pv.z;
            float go = gv.w + pv.w;
            float ii = sigm(gi), ff = sigm(gf), tg = tanh_fast(gg), oo = sigm(go);
            c = ff * c + ii * tg;
            float hn = oo * tanh_fast(c);
            h_sh[nxt][t] = hn;
            if (s < SS - 1) {
                hbuf[s & 7] = hn;
                if ((s & 7) == 7) {                 // batched H store, 1/8 steps
#pragma unroll
                    for (int k2 = 0; k2 < 8; ++k2) {
                        float f = hbuf[k2];
                        unsigned short hi = f2bf(f);
                        Hhi[(s - 6 + k2) * DD + t] = hi;
                        Hlo[(s - 6 + k2) * DD + t] = f2bf(f - bf2f(hi));
                    }
                }
            }
        }
        __syncthreads();
    }
    if (t < DD) {                                   // steps 504..510 -> H[505..511]
#pragma unroll
        for (int k2 = 0; k2 < 7; ++k2) {
            float f = hbuf[k2];
            unsigned short hi = f2bf(f);
            Hhi[(505 + k2) * DD + t] = hi;
            Hlo[(505 + k2) * DD + t] = f2bf(f - bf2f(hi));
        }
    }
}

// ------- phase C: MFMA GEMM logits + masked-softmax epilogue -------------------
// Grid 2500: b = blk>>2 (64-row tile), (blk&3, wave) -> 32-step group.
__global__ __launch_bounds__(256, 1) void k_logits(
        const unsigned short* __restrict__ emb_hi,
        const unsigned short* __restrict__ emb_lo,
        const unsigned short* __restrict__ Hhi,
        const unsigned short* __restrict__ Hlo,
        const unsigned long long* __restrict__ selw,
        const unsigned long long* __restrict__ goodw,
        float* __restrict__ part) {
    int blk = blockIdx.x;
    int b = blk >> 2;
    int t = threadIdx.x, wv = t >> 6, l = t & 63;
    int s0 = (blk & 3) * 128 + wv * 32;
    int ln = l & 31, lh = l >> 5;
    int rb = b * 64;
    const short8* A0h = (const short8*)(emb_hi + (rb + ln) * DD + lh * 8);
    const short8* A0l = (const short8*)(emb_lo + (rb + ln) * DD + lh * 8);
    const short8* A1h = (const short8*)(emb_hi + (rb + 32 + ln) * DD + lh * 8);
    const short8* A1l = (const short8*)(emb_lo + (rb + 32 + ln) * DD + lh * 8);
    const short8* Bhp = (const short8*)(Hhi + (s0 + ln) * DD + lh * 8);
    const short8* Blp = (const short8*)(Hlo + (s0 + ln) * DD + lh * 8);
    f32x16 acc0, acc1;
#pragma unroll
    for (int r = 0; r < 16; ++r) { acc0[r] = 0.f; acc1[r] = 0.f; }
#pragma unroll
    for (int kc = 0; kc < 8; ++kc) {               // K = 8 x 16
        short8 a0h = A0h[kc * 2], a0l = A0l[kc * 2];
        short8 a1h = A1h[kc * 2], a1l = A1l[kc * 2];
        short8 bh = Bhp[kc * 2], bl = Blp[kc * 2];
        acc0 = __builtin_amdgcn_mfma_f32_32x32x16_bf16(a0h, bh, acc0, 0, 0, 0);
        acc0 = __builtin_amdgcn_mfma_f32_32x32x16_bf16(a0l, bh, acc0, 0, 0, 0);
        acc0 = __builtin_amdgcn_mfma_f32_32x32x16_bf16(a0h, bl, acc0, 0, 0, 0);
        acc1 = __builtin_amdgcn_mfma_f32_32x32x16_bf16(a1h, bh, acc1, 0, 0, 0);
        acc1 = __builtin_amdgcn_mfma_f32_32x32x16_bf16(a1l, bh, acc1, 0, 0, 0);
        acc1 = __builtin_amdgcn_mfma_f32_32x32x16_bf16(a1h, bl, acc1, 0, 0, 0);
    }
    int s = s0 + ln;
    unsigned long long sw = selw[b * SS + s];      // coalesced, [b][s] layout
    unsigned long long gw = goodw[b * SS + s];
    float m = NEGF;
#pragma unroll
    for (int r = 0; r < 16; ++r) {
        int row = (r & 3) + 8 * (r >> 2) + 4 * lh;
        float v0 = acc0[r], v1 = acc1[r];
        m = fmaxf(m, ((sw >> row) & 1ull) ? v0 : NEGF);
        m = fmaxf(m, ((sw >> (row + 32)) & 1ull) ? v1 : NEGF);
    }
    m = fmaxf(m, __shfl_xor(m, 32));
    float se = 0.f, sl = 0.f, slg = 0.f;
#pragma unroll
    for (int r = 0; r < 16; ++r) {
        int row = (r & 3) + 8 * (r >> 2) + 4 * lh;
        float v0 = acc0[r], v1 = acc1[r];
        float e0 = ((sw >> row) & 1ull) ? __expf(v0 - m) : 0.f;
        float e1 = ((sw >> (row + 32)) & 1ull) ? __expf(v1 - m) : 0.f;
        se += e0 + e1;
        sl += e0 * v0 + e1 * v1;
        slg += (((gw >> row) & 1ull) ? v0 : 0.f)
             + (((gw >> (row + 32)) & 1ull) ? v1 : 0.f);
    }
    se += __shfl_xor(se, 32);
    sl += __shfl_xor(sl, 32);
    slg += __shfl_xor(slg, 32);
    if (lh == 0) {
        int o = s * NW + b;                        // TRANSPOSED part: [s][b]
        part[0 * PARTN + o] = m;
        part[1 * PARTN + o] = se;
        part[2 * PARTN + o] = sl;
        part[3 * PARTN + o] = slg;
        part[4 * PARTN + o] = (float)__popcll(sw);
        part[5 * PARTN + o] = (float)__popcll(gw);
    }
}

// ------- per-step merge of 625 block partials (coalesced [s][b] reads) ---------
__global__ __launch_bounds__(64) void k_reduce(const float* __restrict__ part,
                                               float* __restrict__ Aout,
                                               float* __restrict__ Bout,
                                               float* __restrict__ actout) {
    int s = blockIdx.x;
    int t = threadIdx.x;     // 64 threads, one wave
    float m = NEGF, se = 0.f, sl = 0.f, slg = 0.f, np = 0.f, ng = 0.f;
    for (int b = t; b < NW; b += 64) {
        int o = s * NW + b;                        // lanes consecutive
        float m2  = part[0 * PARTN + o];
        float se2 = part[1 * PARTN + o];
        float sl2 = part[2 * PARTN + o];
        slg += part[3 * PARTN + o];
        np  += part[4 * PARTN + o];
        ng  += part[5 * PARTN + o];
        float nm = fmaxf(m, m2);
        float a = __expf(m - nm), a2 = __expf(m2 - nm);
        se = se * a + se2 * a2;
        sl = sl * a + sl2 * a2;
        m = nm;
    }
    for (int off = 32; off > 0; off >>= 1) {
        float m2  = __shfl_xor(m, off);
        float se2 = __shfl_xor(se, off);
        float sl2 = __shfl_xor(sl, off);
        slg += __shfl_xor(slg, off);
        np  += __shfl_xor(np, off);
        ng  += __shfl_xor(ng, off);
        float nm = fmaxf(m, m2);
        float a = __expf(m - nm), a2 = __expf(m2 - nm);
        se = se * a + se2 * a2;
        sl = sl * a + sl2 * a2;
        m = nm;
    }
    if (t == 0) {
        float lse = m + logf(se);
        float nbad = np - ng;
        int active = (ng > 0.5f) && (nbad > 0.5f);
        float ce = (ng * lse - slg) / fmaxf(ng, 1.f);
        float A = (nbad / fmaxf(np, 1.f)) * ce;
        float minus_ent = sl / se - lse;
        float B = ECOEF * (minus_ent / logf(fmaxf(np, 2.0f)));
        Aout[s] = A; Bout[s] = B; actout[s] = active ? 1.f : 0.f;
    }
}

// ---------------- exact sequential discount prefix + final sum -----------------
__global__ __launch_bounds__(64) void k_final(const float* __restrict__ A,
                                              const float* __restrict__ B,
                                              const float* __restrict__ act,
                                              float* __restrict__ out) {
    int lane = threadIdx.x;
    float loss = 0.f;
    int base = 0;
    for (int ch = 0; ch < 8; ++ch) {
        int s = ch * 64 + lane;
        bool a = act[s] > 0.5f;
        unsigned long long bal = __ballot(a);
        unsigned long long ltmask = (lane == 0) ? 0ull : (~0ull >> (64 - lane));
        int pre = __popcll(bal & ltmask);
        if (a) {
            float f = powf(DISCOUNT, (float)(base + pre));
            loss += f * A[s] + B[s];
        }
        base += __popcll(bal);
    }
    for (int off = 32; off > 0; off >>= 1) loss += __shfl_xor(loss, off);
    if (lane == 0) out[0] = loss / fmaxf((float)base, 1.f);
}

extern "C" void kernel_launch(void* const* d_in, const int* in_sizes, int n_in,
                              void* d_out, int out_size, void* d_ws, size_t ws_size,
                              hipStream_t stream) {
    (void)in_sizes; (void)n_in; (void)out_size; (void)ws_size;
    const float* feat    = (const float*)d_in[0];
    const int*   sel     = (const int*)d_in[1];
    const int*   good    = (const int*)d_in[2];
    const int*   sel_idx = (const int*)d_in[3];
    const float* W1      = (const float*)d_in[4];
    const float* b1      = (const float*)d_in[5];
    const float* W2      = (const float*)d_in[6];
    const float* b2      = (const float*)d_in[7];
    const float* init_h  = (const float*)d_in[8];
    const float* init_c  = (const float*)d_in[9];
    const float* Wih     = (const float*)d_in[10];
    const float* Whh     = (const float*)d_in[11];
    const float* bih     = (const float*)d_in[12];
    const float* bhh     = (const float*)d_in[13];
    float* out = (float*)d_out;
    char* ws = (char*)d_ws;

    float*          hidden = (float*)(ws + 0);                    // 20,480,000 B
    unsigned short* emb_hi = (unsigned short*)(ws + 20480000);    // 10,240,000 B
    unsigned short* emb_lo = (unsigned short*)(ws + 30720000);    // 10,240,000 B
    float*          P2     = (float*)(ws + 40960000);             //  1,048,576 B
    unsigned short* Hhi    = (unsigned short*)(ws + 42008576);    //    131,072 B
    unsigned short* Hlo    = (unsigned short*)(ws + 42139648);    //    131,072 B
    unsigned long long* selw  = (unsigned long long*)(ws + 42270720);  // 2,560,000 B
    unsigned long long* goodw = (unsigned long long*)(ws + 44830720);  // 2,560,000 B
    float*          part   = (float*)(ws + 47390720);             //  7,680,000 B
    float*          Aarr   = (float*)(ws + 55070720);             //      2,048 B
    float*          Barr   = (float*)(ws + 55072768);             //      2,048 B
    float*          actarr = (float*)(ws + 55074816);             //      2,048 B

    k_pack  <<<1250, 256, 0, stream>>>(sel, good, selw, goodw);
    k_hidden<<<N_CL / 2, 256, 0, stream>>>(feat, W1, b1, hidden);
    k_emb   <<<NW, 256, 0, stream>>>(hidden, W2, b2, emb_hi, emb_lo);
    k_pgemm <<<64, 256, 0, stream>>>(emb_hi, emb_lo, sel_idx, Wih, bih, bhh, P2);
    k_lstm  <<<1, 512, 0, stream>>>(Whh, P2, init_h, init_c, Hhi, Hlo);
    k_logits<<<NW * 4, 256, 0, stream>>>(emb_hi, emb_lo, Hhi, Hlo, selw, goodw, part);
    k_reduce<<<SS, 64, 0, stream>>>(part, Aarr, Barr, actarr);
    k_final <<<1, 64, 0, stream>>>(Aarr, Barr, actarr, out);
}

// Round 12
// 837.594 us; speedup vs baseline: 1.4107x; 1.0927x over previous
//
#include <hip/hip_runtime.h>
#include <stdint.h>

#define N_CL 40000
#define NF   20
#define DD   128
#define SS   512
#define NW   625                 // N_CL / 64
#define PARTN (NW * SS)
#define NEGF (-3.0e38f)
#define DISCOUNT 0.995f
#define ECOEF 0.1f

typedef __attribute__((ext_vector_type(4))) float f32x4;
typedef __attribute__((ext_vector_type(16))) float f32x16;
typedef __attribute__((ext_vector_type(8))) short short8;
typedef __attribute__((ext_vector_type(4))) unsigned short us4;

__device__ __forceinline__ float rcpf(float x) { return __builtin_amdgcn_rcpf(x); }
__device__ __forceinline__ float sigm(float x) { return rcpf(1.f + __expf(-x)); }
__device__ __forceinline__ float tanh_fast(float x) { return 1.f - 2.f * rcpf(1.f + __expf(2.f * x)); }
__device__ __forceinline__ unsigned short f2bf(float f) {
    unsigned u = __float_as_uint(f);
    return (unsigned short)((u + 0x7fffu + ((u >> 16) & 1u)) >> 16);   // RNE
}
__device__ __forceinline__ float bf2f(unsigned short s) {
    return __uint_as_float(((unsigned)s) << 16);
}

// ------- pack masks: ballot -> u64 words, TRANSPOSED layout [b][s] -------------
__global__ __launch_bounds__(256) void k_pack(const int* __restrict__ sel,
                                              const int* __restrict__ good,
                                              unsigned long long* __restrict__ selw,
                                              unsigned long long* __restrict__ goodw) {
    int wave = (blockIdx.x * 256 + threadIdx.x) >> 6;   // 0..4999
    int lane = threadIdx.x & 63;
    for (int i = 0; i < 64; ++i) {
        int chunk = wave * 64 + i;                      // 0..319999
        int s = chunk / NW;
        int b = chunk - s * NW;
        int idx = s * N_CL + b * 64 + lane;
        unsigned long long bs = __ballot(sel[idx]  != 0);
        unsigned long long bg = __ballot(good[idx] != 0);
        if (lane == 0) { selw[b * SS + s] = bs; goodw[b * SS + s] = bg; }
    }
}

// ---------------- hidden = relu(features @ W1 + b1) ----------------------------
__global__ __launch_bounds__(256) void k_hidden(const float* __restrict__ feat,
                                                const float* __restrict__ W1,
                                                const float* __restrict__ b1,
                                                float* __restrict__ hidden) {
    int t = threadIdx.x;
    int j = t & 127;
    int r = blockIdx.x * 2 + (t >> 7);
    const float* fr = feat + r * NF;
    float acc = b1[j];
#pragma unroll
    for (int f = 0; f < NF; ++f) acc += fr[f] * W1[f * DD + j];
    hidden[r * DD + j] = fmaxf(acc, 0.f);
}

// ------- emb = hidden @ W2 + b2, emitted as bf16 hi/lo pairs -------------------
#define EMB_FMA(RR) { f32x4 hvv = *(const f32x4*)&hs[rg * 8 + RR][q]; \
    acc##RR += wv0 * hvv.x + wv1 * hvv.y + wv2 * hvv.z + wv3 * hvv.w; }
#define EMB_ST(RR) { f32x4 f = acc##RR + bv; us4 hi, lo; \
    hi[0] = f2bf(f.x); lo[0] = f2bf(f.x - bf2f(hi[0])); \
    hi[1] = f2bf(f.y); lo[1] = f2bf(f.y - bf2f(hi[1])); \
    hi[2] = f2bf(f.z); lo[2] = f2bf(f.z - bf2f(hi[2])); \
    hi[3] = f2bf(f.w); lo[3] = f2bf(f.w - bf2f(hi[3])); \
    int row_ = rbase + rg * 8 + RR; \
    *(us4*)&emb_hi[row_ * DD + c4 * 4] = hi; \
    *(us4*)&emb_lo[row_ * DD + c4 * 4] = lo; }

__global__ __launch_bounds__(256) void k_emb(const float* __restrict__ hidden,
                                             const float* __restrict__ W2,
                                             const float* __restrict__ b2,
                                             unsigned short* __restrict__ emb_hi,
                                             unsigned short* __restrict__ emb_lo) {
    __shared__ float hs[64][132];                     // +4 pad, 33.8 KB
    int t = threadIdx.x;
    int rbase = blockIdx.x * 64;
#pragma unroll
    for (int i = t; i < 2048; i += 256) {             // stage 64x128 hidden tile
        int r = i >> 5, k4 = i & 31;
        *(f32x4*)&hs[r][k4 * 4] = *(const f32x4*)&hidden[(rbase + r) * DD + k4 * 4];
    }
    __syncthreads();
    int c4 = t & 31, rg = t >> 5;
    f32x4 acc0{0,0,0,0}, acc1{0,0,0,0}, acc2{0,0,0,0}, acc3{0,0,0,0},
          acc4{0,0,0,0}, acc5{0,0,0,0}, acc6{0,0,0,0}, acc7{0,0,0,0};
    for (int q = 0; q < DD; q += 4) {
        f32x4 wv0 = *(const f32x4*)&W2[(q + 0) * DD + c4 * 4];
        f32x4 wv1 = *(const f32x4*)&W2[(q + 1) * DD + c4 * 4];
        f32x4 wv2 = *(const f32x4*)&W2[(q + 2) * DD + c4 * 4];
        f32x4 wv3 = *(const f32x4*)&W2[(q + 3) * DD + c4 * 4];
        EMB_FMA(0) EMB_FMA(1) EMB_FMA(2) EMB_FMA(3)
        EMB_FMA(4) EMB_FMA(5) EMB_FMA(6) EMB_FMA(7)
    }
    f32x4 bv = *(const f32x4*)&b2[c4 * 4];
    EMB_ST(0) EMB_ST(1) EMB_ST(2) EMB_ST(3)
    EMB_ST(4) EMB_ST(5) EMB_ST(6) EMB_ST(7)
}

// ---- P2[s][pos][g] = bih[j]+bhh[j]+Wih[j].emb[sel_idx[s]],  j=g*128+pos ------
__global__ __launch_bounds__(256) void k_pgemm(const unsigned short* __restrict__ emb_hi,
                                               const unsigned short* __restrict__ emb_lo,
                                               const int* __restrict__ sel_idx,
                                               const float* __restrict__ Wih,
                                               const float* __restrict__ bih,
                                               const float* __restrict__ bhh,
                                               float* __restrict__ P2) {
    __shared__ __align__(16) float x8[8][DD];
    int t = threadIdx.x;
    int sb = blockIdx.x * 8;
    for (int i = t; i < 8 * DD; i += 256) {
        int sl = i >> 7, k = i & 127;
        int idx = sel_idx[sb + sl] * DD + k;
        x8[sl][k] = bf2f(emb_hi[idx]) + bf2f(emb_lo[idx]);
    }
    __syncthreads();
    for (int jj = t; jj < 512; jj += 256) {
        float base = bih[jj] + bhh[jj];
        float acc[8];
#pragma unroll
        for (int s8 = 0; s8 < 8; ++s8) acc[s8] = base;
        const float4* wr = (const float4*)(Wih + jj * DD);
        for (int q = 0; q < 32; ++q) {
            float4 w4 = wr[q];
#pragma unroll
            for (int s8 = 0; s8 < 8; ++s8) {
                const float4* xs = (const float4*)&x8[s8][0];
                float4 xv = xs[q];
                acc[s8] += w4.x * xv.x + w4.y * xv.y + w4.z * xv.z + w4.w * xv.w;
            }
        }
        int pos = jj & 127, g = jj >> 7;
        for (int s8 = 0; s8 < 8; ++s8) P2[(sb + s8) * 512 + pos * 4 + g] = acc[s8];
    }
}

// ------- sequential LSTM scan: quarter-K split, 4 rows/thread, pk-fma ----------
// 512 threads = 8 waves (2/SIMD). Wave w: K-quarter kq=w&3, gate-half gh=w>>2.
// Lane l: rows gbase..gbase+3 (gbase = gh*256 + l*4) over K [kq*32, kq*32+32).
// h broadcast: only 8 ds_read_b128 per wave (64/step vs r11's 256 -> 4x less
// LDS return traffic). Partials -> psum[4][512] via ONE conflict-free
// ds_write_b128/thread; elementwise sums quarters with stride-1 reads.
#define MQ(Q) { f32x4 hv = hp[Q]; \
    a0 += w0##Q * hv; a1 += w1##Q * hv; a2 += w2##Q * hv; a3 += w3##Q * hv; }

__global__ __launch_bounds__(512, 1) void k_lstm(const float* __restrict__ Whh,
                                                 const float* __restrict__ P2,
                                                 const float* __restrict__ init_h,
                                                 const float* __restrict__ init_c,
                                                 unsigned short* __restrict__ Hhi,
                                                 unsigned short* __restrict__ Hlo) {
    __shared__ __align__(16) float pbuf[2][4096];   // 32 KB: two 8-step P chunks
    __shared__ __align__(16) float psum[4][512];    // [kq][row]
    __shared__ __align__(16) float h_sh[2][DD];     // double-buffered hidden
    int t = threadIdx.x, w = t >> 6, l = t & 63;
    int kq = w & 3, gh = w >> 2;
    int gbase = gh * 256 + l * 4;

    const f32x4* wr0 = (const f32x4*)(Whh + (gbase + 0) * DD + kq * 32);
    const f32x4* wr1 = (const f32x4*)(Whh + (gbase + 1) * DD + kq * 32);
    const f32x4* wr2 = (const f32x4*)(Whh + (gbase + 2) * DD + kq * 32);
    const f32x4* wr3 = (const f32x4*)(Whh + (gbase + 3) * DD + kq * 32);
    f32x4 w00 = wr0[0], w01 = wr0[1], w02 = wr0[2], w03 = wr0[3],
          w04 = wr0[4], w05 = wr0[5], w06 = wr0[6], w07 = wr0[7];
    f32x4 w10 = wr1[0], w11 = wr1[1], w12 = wr1[2], w13 = wr1[3],
          w14 = wr1[4], w15 = wr1[5], w16 = wr1[6], w17 = wr1[7];
    f32x4 w20 = wr2[0], w21 = wr2[1], w22 = wr2[2], w23 = wr2[3],
          w24 = wr2[4], w25 = wr2[5], w26 = wr2[6], w27 = wr2[7];
    f32x4 w30 = wr3[0], w31 = wr3[1], w32 = wr3[2], w33 = wr3[3],
          w34 = wr3[4], w35 = wr3[5], w36 = wr3[6], w37 = wr3[7];

    auto issue = [&](int cidx, int bufi) {          // stage one 8-step P chunk
        if (cidx >= SS / 8) return;
        const float* src = P2 + cidx * 4096 + w * 512 + l * 4;
        float* dst = &pbuf[bufi][w * 512];
#pragma unroll
        for (int i = 0; i < 2; ++i) {
            __builtin_amdgcn_global_load_lds(
                (const __attribute__((address_space(1))) void*)(src + i * 256),
                (__attribute__((address_space(3))) void*)(dst + i * 256),
                16, 0, 0);
        }
    };

    float c = 0.f;
    if (t < DD) {
        float f = init_h[t];
        h_sh[0][t] = f; c = init_c[t];
        unsigned short hi = f2bf(f);
        Hhi[t] = hi; Hlo[t] = f2bf(f - bf2f(hi));
    }
    issue(0, 0);
    __syncthreads();

    float hbuf[8];
    for (int s = 0; s < SS; ++s) {
        int cur = s & 1, nxt = cur ^ 1;
        int buf = (s >> 3) & 1;
        if ((s & 7) == 0) issue((s >> 3) + 1, buf ^ 1);
        const f32x4* hp = (const f32x4*)&h_sh[cur][kq * 32];  // wave-uniform bcast
        f32x4 a0{0,0,0,0}, a1{0,0,0,0}, a2{0,0,0,0}, a3{0,0,0,0};
        MQ(0) MQ(1) MQ(2) MQ(3) MQ(4) MQ(5) MQ(6) MQ(7)
        f32x4 ps;
        ps.x = (a0.x + a0.y) + (a0.z + a0.w);
        ps.y = (a1.x + a1.y) + (a1.z + a1.w);
        ps.z = (a2.x + a2.y) + (a2.z + a2.w);
        ps.w = (a3.x + a3.y) + (a3.z + a3.w);
        *(f32x4*)&psum[kq][gbase] = ps;             // stride-16B, conflict-free
        __syncthreads();
        if (t < DD) {
            float4 pv = *(const float4*)&pbuf[buf][(s & 7) * 512 + t * 4];
            float gi = ((psum[0][t]       + psum[1][t])       + (psum[2][t]       + psum[3][t]))       + pv.x;
            float gf = ((psum[0][128 + t] + psum[1][128 + t]) + (psum[2][128 + t] + psum[3][128 + t])) + pv.y;
            float gg = ((psum[0][256 + t] + psum[1][256 + t]) + (psum[2][256 + t] + psum[3][256 + t])) + pv.z;
            float go = ((psum[0][384 + t] + psum[1][384 + t]) + (psum[2][384 + t] + psum[3][384 + t])) + pv.w;
            float ii = sigm(gi), ff = sigm(gf), tg = tanh_fast(gg), oo = sigm(go);
            c = ff * c + ii * tg;
            float hn = oo * tanh_fast(c);
            h_sh[nxt][t] = hn;
            if (s < SS - 1) {
                hbuf[s & 7] = hn;
                if ((s & 7) == 7) {                 // batched H store, 1/8 steps
#pragma unroll
                    for (int k2 = 0; k2 < 8; ++k2) {
                        float f = hbuf[k2];
                        unsigned short hi = f2bf(f);
                        Hhi[(s - 6 + k2) * DD + t] = hi;
                        Hlo[(s - 6 + k2) * DD + t] = f2bf(f - bf2f(hi));
                    }
                }
            }
        }
        __syncthreads();
    }
    if (t < DD) {                                   // steps 504..510 -> H[505..511]
#pragma unroll
        for (int k2 = 0; k2 < 7; ++k2) {
            float f = hbuf[k2];
            unsigned short hi = f2bf(f);
            Hhi[(505 + k2) * DD + t] = hi;
            Hlo[(505 + k2) * DD + t] = f2bf(f - bf2f(hi));
        }
    }
}

// ------- phase C: MFMA GEMM logits + masked-softmax epilogue -------------------
// Grid 2500: b = blk>>2 (64-row tile), (blk&3, wave) -> 32-step group.
__global__ __launch_bounds__(256, 1) void k_logits(
        const unsigned short* __restrict__ emb_hi,
        const unsigned short* __restrict__ emb_lo,
        const unsigned short* __restrict__ Hhi,
        const unsigned short* __restrict__ Hlo,
        const unsigned long long* __restrict__ selw,
        const unsigned long long* __restrict__ goodw,
        float* __restrict__ part) {
    int blk = blockIdx.x;
    int b = blk >> 2;
    int t = threadIdx.x, wv = t >> 6, l = t & 63;
    int s0 = (blk & 3) * 128 + wv * 32;
    int ln = l & 31, lh = l >> 5;
    int rb = b * 64;
    const short8* A0h = (const short8*)(emb_hi + (rb + ln) * DD + lh * 8);
    const short8* A0l = (const short8*)(emb_lo + (rb + ln) * DD + lh * 8);
    const short8* A1h = (const short8*)(emb_hi + (rb + 32 + ln) * DD + lh * 8);
    const short8* A1l = (const short8*)(emb_lo + (rb + 32 + ln) * DD + lh * 8);
    const short8* Bhp = (const short8*)(Hhi + (s0 + ln) * DD + lh * 8);
    const short8* Blp = (const short8*)(Hlo + (s0 + ln) * DD + lh * 8);
    f32x16 acc0, acc1;
#pragma unroll
    for (int r = 0; r < 16; ++r) { acc0[r] = 0.f; acc1[r] = 0.f; }
#pragma unroll
    for (int kc = 0; kc < 8; ++kc) {               // K = 8 x 16
        short8 a0h = A0h[kc * 2], a0l = A0l[kc * 2];
        short8 a1h = A1h[kc * 2], a1l = A1l[kc * 2];
        short8 bh = Bhp[kc * 2], bl = Blp[kc * 2];
        acc0 = __builtin_amdgcn_mfma_f32_32x32x16_bf16(a0h, bh, acc0, 0, 0, 0);
        acc0 = __builtin_amdgcn_mfma_f32_32x32x16_bf16(a0l, bh, acc0, 0, 0, 0);
        acc0 = __builtin_amdgcn_mfma_f32_32x32x16_bf16(a0h, bl, acc0, 0, 0, 0);
        acc1 = __builtin_amdgcn_mfma_f32_32x32x16_bf16(a1h, bh, acc1, 0, 0, 0);
        acc1 = __builtin_amdgcn_mfma_f32_32x32x16_bf16(a1l, bh, acc1, 0, 0, 0);
        acc1 = __builtin_amdgcn_mfma_f32_32x32x16_bf16(a1h, bl, acc1, 0, 0, 0);
    }
    int s = s0 + ln;
    unsigned long long sw = selw[b * SS + s];      // coalesced, [b][s] layout
    unsigned long long gw = goodw[b * SS + s];
    float m = NEGF;
#pragma unroll
    for (int r = 0; r < 16; ++r) {
        int row = (r & 3) + 8 * (r >> 2) + 4 * lh;
        float v0 = acc0[r], v1 = acc1[r];
        m = fmaxf(m, ((sw >> row) & 1ull) ? v0 : NEGF);
        m = fmaxf(m, ((sw >> (row + 32)) & 1ull) ? v1 : NEGF);
    }
    m = fmaxf(m, __shfl_xor(m, 32));
    float se = 0.f, sl = 0.f, slg = 0.f;
#pragma unroll
    for (int r = 0; r < 16; ++r) {
        int row = (r & 3) + 8 * (r >> 2) + 4 * lh;
        float v0 = acc0[r], v1 = acc1[r];
        float e0 = ((sw >> row) & 1ull) ? __expf(v0 - m) : 0.f;
        float e1 = ((sw >> (row + 32)) & 1ull) ? __expf(v1 - m) : 0.f;
        se += e0 + e1;
        sl += e0 * v0 + e1 * v1;
        slg += (((gw >> row) & 1ull) ? v0 : 0.f)
             + (((gw >> (row + 32)) & 1ull) ? v1 : 0.f);
    }
    se += __shfl_xor(se, 32);
    sl += __shfl_xor(sl, 32);
    slg += __shfl_xor(slg, 32);
    if (lh == 0) {
        int o = s * NW + b;                        // TRANSPOSED part: [s][b]
        part[0 * PARTN + o] = m;
        part[1 * PARTN + o] = se;
        part[2 * PARTN + o] = sl;
        part[3 * PARTN + o] = slg;
        part[4 * PARTN + o] = (float)__popcll(sw);
        part[5 * PARTN + o] = (float)__popcll(gw);
    }
}

// ------- per-step merge of 625 block partials (coalesced [s][b] reads) ---------
__global__ __launch_bounds__(64) void k_reduce(const float* __restrict__ part,
                                               float* __restrict__ Aout,
                                               float* __restrict__ Bout,
                                               float* __restrict__ actout) {
    int s = blockIdx.x;
    int t = threadIdx.x;     // 64 threads, one wave
    float m = NEGF, se = 0.f, sl = 0.f, slg = 0.f, np = 0.f, ng = 0.f;
    for (int b = t; b < NW; b += 64) {
        int o = s * NW + b;                        // lanes consecutive
        float m2  = part[0 * PARTN + o];
        float se2 = part[1 * PARTN + o];
        float sl2 = part[2 * PARTN + o];
        slg += part[3 * PARTN + o];
        np  += part[4 * PARTN + o];
        ng  += part[5 * PARTN + o];
        float nm = fmaxf(m, m2);
        float a = __expf(m - nm), a2 = __expf(m2 - nm);
        se = se * a + se2 * a2;
        sl = sl * a + sl2 * a2;
        m = nm;
    }
    for (int off = 32; off > 0; off >>= 1) {
        float m2  = __shfl_xor(m, off);
        float se2 = __shfl_xor(se, off);
        float sl2 = __shfl_xor(sl, off);
        slg += __shfl_xor(slg, off);
        np  += __shfl_xor(np, off);
        ng  += __shfl_xor(ng, off);
        float nm = fmaxf(m, m2);
        float a = __expf(m - nm), a2 = __expf(m2 - nm);
        se = se * a + se2 * a2;
        sl = sl * a + sl2 * a2;
        m = nm;
    }
    if (t == 0) {
        float lse = m + logf(se);
        float nbad = np - ng;
        int active = (ng > 0.5f) && (nbad > 0.5f);
        float ce = (ng * lse - slg) / fmaxf(ng, 1.f);
        float A = (nbad / fmaxf(np, 1.f)) * ce;
        float minus_ent = sl / se - lse;
        float B = ECOEF * (minus_ent / logf(fmaxf(np, 2.0f)));
        Aout[s] = A; Bout[s] = B; actout[s] = active ? 1.f : 0.f;
    }
}

// ---------------- exact sequential discount prefix + final sum -----------------
__global__ __launch_bounds__(64) void k_final(const float* __restrict__ A,
                                              const float* __restrict__ B,
                                              const float* __restrict__ act,
                                              float* __restrict__ out) {
    int lane = threadIdx.x;
    float loss = 0.f;
    int base = 0;
    for (int ch = 0; ch < 8; ++ch) {
        int s = ch * 64 + lane;
        bool a = act[s] > 0.5f;
        unsigned long long bal = __ballot(a);
        unsigned long long ltmask = (lane == 0) ? 0ull : (~0ull >> (64 - lane));
        int pre = __popcll(bal & ltmask);
        if (a) {
            float f = powf(DISCOUNT, (float)(base + pre));
            loss += f * A[s] + B[s];
        }
        base += __popcll(bal);
    }
    for (int off = 32; off > 0; off >>= 1) loss += __shfl_xor(loss, off);
    if (lane == 0) out[0] = loss / fmaxf((float)base, 1.f);
}

extern "C" void kernel_launch(void* const* d_in, const int* in_sizes, int n_in,
                              void* d_out, int out_size, void* d_ws, size_t ws_size,
                              hipStream_t stream) {
    (void)in_sizes; (void)n_in; (void)out_size; (void)ws_size;
    const float* feat    = (const float*)d_in[0];
    const int*   sel     = (const int*)d_in[1];
    const int*   good    = (const int*)d_in[2];
    const int*   sel_idx = (const int*)d_in[3];
    const float* W1      = (const float*)d_in[4];
    const float* b1      = (const float*)d_in[5];
    const float* W2      = (const float*)d_in[6];
    const float* b2      = (const float*)d_in[7];
    const float* init_h  = (const float*)d_in[8];
    const float* init_c  = (const float*)d_in[9];
    const float* Wih     = (const float*)d_in[10];
    const float* Whh     = (const float*)d_in[11];
    const float* bih     = (const float*)d_in[12];
    const float* bhh     = (const float*)d_in[13];
    float* out = (float*)d_out;
    char* ws = (char*)d_ws;

    float*          hidden = (float*)(ws + 0);                    // 20,480,000 B
    unsigned short* emb_hi = (unsigned short*)(ws + 20480000);    // 10,240,000 B
    unsigned short* emb_lo = (unsigned short*)(ws + 30720000);    // 10,240,000 B
    float*          P2     = (float*)(ws + 40960000);             //  1,048,576 B
    unsigned short* Hhi    = (unsigned short*)(ws + 42008576);    //    131,072 B
    unsigned short* Hlo    = (unsigned short*)(ws + 42139648);    //    131,072 B
    unsigned long long* selw  = (unsigned long long*)(ws + 42270720);  // 2,560,000 B
    unsigned long long* goodw = (unsigned long long*)(ws + 44830720);  // 2,560,000 B
    float*          part   = (float*)(ws + 47390720);             //  7,680,000 B
    float*          Aarr   = (float*)(ws + 55070720);             //      2,048 B
    float*          Barr   = (float*)(ws + 55072768);             //      2,048 B
    float*          actarr = (float*)(ws + 55074816);             //      2,048 B

    k_pack  <<<1250, 256, 0, stream>>>(sel, good, selw, goodw);
    k_hidden<<<N_CL / 2, 256, 0, stream>>>(feat, W1, b1, hidden);
    k_emb   <<<NW, 256, 0, stream>>>(hidden, W2, b2, emb_hi, emb_lo);
    k_pgemm <<<64, 256, 0, stream>>>(emb_hi, emb_lo, sel_idx, Wih, bih, bhh, P2);
    k_lstm  <<<1, 512, 0, stream>>>(Whh, P2, init_h, init_c, Hhi, Hlo);
    k_logits<<<NW * 4, 256, 0, stream>>>(emb_hi, emb_lo, Hhi, Hlo, selw, goodw, part);
    k_reduce<<<SS, 64, 0, stream>>>(part, Aarr, Barr, actarr);
    k_final <<<1, 64, 0, stream>>>(Aarr, Barr, actarr, out);
}